// Round 4
// baseline (530.724 us; speedup 1.0000x reference)
//
#include <hip/hip_runtime.h>
#include <hip/hip_bf16.h>

// Problem constants
#define B_DIM   512
#define IN_DIM  4096
#define OUT_DIM 11008

typedef __bf16 bf16x4  __attribute__((ext_vector_type(4)));
typedef __bf16 bf16x8  __attribute__((ext_vector_type(8)));
typedef float  floatx4 __attribute__((ext_vector_type(4)));
typedef int    intx4   __attribute__((ext_vector_type(4)));

// ---------------------------------------------------------------------------
// x fp32 -> bf16 (4 MB ws traffic; ~3 us)
// ---------------------------------------------------------------------------
__global__ __launch_bounds__(256) void conv_x_kernel(
    const float* __restrict__ x, __bf16* __restrict__ xb) {
  int idx = blockIdx.x * blockDim.x + threadIdx.x;  // quad index
  float4 v = ((const float4*)x)[idx];
  bf16x4 o;
  o[0] = (__bf16)v.x; o[1] = (__bf16)v.y; o[2] = (__bf16)v.z; o[3] = (__bf16)v.w;
  ((bf16x4*)xb)[idx] = o;
}

// ---------------------------------------------------------------------------
// Fused decode + GEMM, software-pipelined WITHOUT global_load_lds.
// C(512 x 11008) = A(512x4096 bf16) * W^T, W decoded on the fly from
// stored/sign (row-major [N][K] int32).
// BM=512 (all of M): every weight read+decoded exactly once. BN=64, BK=32.
// 512 threads = 8 waves; wave w owns rows [64w,64w+64) x 64 cols
// (4x4 mfma_f32_16x16x32_bf16). Grid = 172.
//  - A-frags: direct global->register bf16x8 loads (A=4MB, L2-resident),
//    prefetched 1 iteration ahead.
//  - B: int4 nontemporal loads prefetched 2 iterations ahead ->
//    __expf decode -> ds_write -> double-buffered sB, ONE barrier/iter.
//    Plain LDS ops only: __syncthreads() ordering is unambiguous.
// ---------------------------------------------------------------------------
__global__ __launch_bounds__(512, 2) void fused_gemm_kernel(
    const __bf16* __restrict__ A,       // 512 x 4096 bf16
    const int* __restrict__ stored,     // 11008 x 4096 int32 in [1,255]
    const int* __restrict__ sign,       // 11008 x 4096 int32 in {-1,+1}
    const float* __restrict__ logmin, const float* __restrict__ logmax,
    const float* __restrict__ scale, const float* __restrict__ bias,
    float* __restrict__ out) {          // 512 x 11008 fp32
  constexpr int K = IN_DIM, N = OUT_DIM;
  constexpr int BK = 32;

  __shared__ __align__(16) __bf16 sB[2][64 * BK];  // 2 x 4 KB

  const int tid  = threadIdx.x;
  const int lane = tid & 63;
  const int wave = tid >> 6;
  const int m16  = lane & 15;
  const int q    = lane >> 4;

  const int bn0 = blockIdx.x * 64;

  const float lmin  = logmin[0];
  const float slope = (logmax[0] - lmin) * (1.0f / 254.0f);

  // B staging: thread t -> tile row t/8 (0..63), k-offset (t&7)*4.
  const int br = tid >> 3;
  const int bc = (tid & 7) * 4;
  const int* gS = stored + (size_t)(bn0 + br) * K + bc;
  const int* gG = sign   + (size_t)(bn0 + br) * K + bc;

  // A-frag base: lane (m16,q) of wave reads A[wave*64 + i*16 + m16][kt + q*8].
  const __bf16* gA = A + (size_t)(wave * 64 + m16) * K + q * 8;

  floatx4 acc[4][4] = {};

  // Validated decode (rounds 1-2): w = sign * exp(lmin + (255-s)*slope)
#define DECODE_STORE(sv, gv, dst)                                              \
  {                                                                            \
    bf16x4 wv;                                                                 \
    wv[0] = (__bf16)(__expf(fmaf((float)(255 - (sv).x), slope, lmin)) *        \
                     (float)(gv).x);                                           \
    wv[1] = (__bf16)(__expf(fmaf((float)(255 - (sv).y), slope, lmin)) *        \
                     (float)(gv).y);                                           \
    wv[2] = (__bf16)(__expf(fmaf((float)(255 - (sv).z), slope, lmin)) *        \
                     (float)(gv).z);                                           \
    wv[3] = (__bf16)(__expf(fmaf((float)(255 - (sv).w), slope, lmin)) *        \
                     (float)(gv).w);                                           \
    *(bf16x4*)(dst) = wv;                                                      \
  }

  // ---- Prologue ----
  // Decode kt=0 into sB[0]; prefetch ints for kt=32 (s0) and kt=64 (s1).
  intx4 sv = __builtin_nontemporal_load((const intx4*)(gS));
  intx4 gv = __builtin_nontemporal_load((const intx4*)(gG));
  bf16x8 afrA[4];
#pragma unroll
  for (int i = 0; i < 4; ++i)
    afrA[i] = *(const bf16x8*)(gA + (size_t)(i * 16) * K);   // kt = 0
  DECODE_STORE(sv, gv, &sB[0][tid * 4]);
  intx4 s0 = __builtin_nontemporal_load((const intx4*)(gS + BK));
  intx4 g0 = __builtin_nontemporal_load((const intx4*)(gG + BK));
  intx4 s1 = __builtin_nontemporal_load((const intx4*)(gS + 2 * BK));
  intx4 g1 = __builtin_nontemporal_load((const intx4*)(gG + 2 * BK));

  // ---- Main loop: one barrier per K-step ----
  int p = 0;
  for (int kt = 0; kt < K; kt += BK, p ^= 1) {
    __syncthreads();  // sB[p] (written last iter) visible; p^1 readers done

    const bool more = (kt + BK) < K;

    // Prefetch next A-frags (L2-resident) into registers.
    bf16x8 afrB[4];
    if (more) {
#pragma unroll
      for (int i = 0; i < 4; ++i)
        afrB[i] = *(const bf16x8*)(gA + (size_t)(i * 16) * K + kt + BK);
    }

    // Current B frags from LDS.
    bf16x8 bfr[4];
#pragma unroll
    for (int i = 0; i < 4; ++i)
      bfr[i] = *(const bf16x8*)&sB[p][(i * 16 + m16) * BK + q * 8];

    // Decode ints (loaded 2 iters ago) for kt+BK into the other buffer;
    // rotate the int prefetch pipe.
    if (more) {
      DECODE_STORE(s0, g0, &sB[p ^ 1][tid * 4]);
      s0 = s1; g0 = g1;
      const int kt3 = (kt + 3 * BK) < K ? (kt + 3 * BK) : 0;  // dummy on tail
      s1 = __builtin_nontemporal_load((const intx4*)(gS + kt3));
      g1 = __builtin_nontemporal_load((const intx4*)(gG + kt3));
    }

#pragma unroll
    for (int mi = 0; mi < 4; ++mi)
#pragma unroll
      for (int ni = 0; ni < 4; ++ni)
        acc[mi][ni] = __builtin_amdgcn_mfma_f32_16x16x32_bf16(
            afrA[mi], bfr[ni], acc[mi][ni], 0, 0, 0);

    if (more) {
#pragma unroll
      for (int i = 0; i < 4; ++i) afrA[i] = afrB[i];
    }
  }

  // Epilogue. C/D layout: col = lane&15, row = q*4 + reg  [m89]
#pragma unroll
  for (int ni = 0; ni < 4; ++ni) {
    const int col = bn0 + ni * 16 + m16;
    const float sc = scale[col];
    const float bb = bias[col] * sc;
#pragma unroll
    for (int mi = 0; mi < 4; ++mi) {
#pragma unroll
      for (int r = 0; r < 4; ++r) {
        const int row = wave * 64 + mi * 16 + q * 4 + r;
        out[(size_t)row * N + col] = acc[mi][ni][r] * sc + bb;
      }
    }
  }
#undef DECODE_STORE
}

// ---------------------------------------------------------------------------
extern "C" void kernel_launch(void* const* d_in, const int* in_sizes, int n_in,
                              void* d_out, int out_size, void* d_ws, size_t ws_size,
                              hipStream_t stream) {
  const float* x      = (const float*)d_in[0];
  const int*   stored = (const int*)d_in[1];
  const int*   sign   = (const int*)d_in[2];
  const float* logmin = (const float*)d_in[3];
  const float* logmax = (const float*)d_in[4];
  const float* scale  = (const float*)d_in[5];
  const float* bias   = (const float*)d_in[6];
  float* out = (float*)d_out;

  __bf16* wsX = (__bf16*)d_ws;  // 512*4096 bf16 = 4 MB

  conv_x_kernel<<<(B_DIM * (IN_DIM / 4)) / 256, 256, 0, stream>>>(x, wsX);
  fused_gemm_kernel<<<OUT_DIM / 64, 512, 0, stream>>>(
      wsX, stored, sign, logmin, logmax, scale, bias, out);
}

// Round 5
// 510.834 us; speedup vs baseline: 1.0389x; 1.0389x over previous
//
#include <hip/hip_runtime.h>
#include <hip/hip_bf16.h>

// Problem constants
#define B_DIM   512
#define IN_DIM  4096
#define OUT_DIM 11008

typedef __bf16 bf16x4  __attribute__((ext_vector_type(4)));
typedef __bf16 bf16x8  __attribute__((ext_vector_type(8)));
typedef float  floatx4 __attribute__((ext_vector_type(4)));
typedef int    intx4   __attribute__((ext_vector_type(4)));

// ---------------------------------------------------------------------------
// x fp32 -> bf16 (4 MB ws traffic; ~3 us)
// ---------------------------------------------------------------------------
__global__ __launch_bounds__(256) void conv_x_kernel(
    const float* __restrict__ x, __bf16* __restrict__ xb) {
  int idx = blockIdx.x * blockDim.x + threadIdx.x;  // quad index
  float4 v = ((const float4*)x)[idx];
  bf16x4 o;
  o[0] = (__bf16)v.x; o[1] = (__bf16)v.y; o[2] = (__bf16)v.z; o[3] = (__bf16)v.w;
  ((bf16x4*)xb)[idx] = o;
}

// ---------------------------------------------------------------------------
// Fused decode + GEMM.  C(512x11008) = A(512x4096 bf16) * W^T.
// BM=512 (all of M, weights decoded EXACTLY once), BN=32, BK=32.
// Grid = 11008/32 = 344 blocks x 256 threads (4 waves).
// Wave w: rows [128w,128w+128) x 32 cols = 8x2 grid of 16x16x32 bf16 MFMA.
// Both operands staged in double-buffered LDS with PLAIN loads/ds_writes
// (one barrier/iter; ordering validated in round 4's sB path).
//  - A: coalesced dwordx4 global loads (L2-resident, 4 MB), 1 iter ahead.
//  - B: int4 nontemporal loads 2 iters ahead -> __expf decode -> ds_write.
// ---------------------------------------------------------------------------
__global__ __launch_bounds__(256, 2) void fused_gemm_kernel(
    const __bf16* __restrict__ A,       // 512 x 4096 bf16
    const int* __restrict__ stored,     // 11008 x 4096 int32 in [1,255]
    const int* __restrict__ sign,       // 11008 x 4096 int32 in {-1,+1}
    const float* __restrict__ logmin, const float* __restrict__ logmax,
    const float* __restrict__ scale, const float* __restrict__ bias,
    float* __restrict__ out) {          // 512 x 11008 fp32
  constexpr int K = IN_DIM, N = OUT_DIM;
  constexpr int BK = 32;

  __shared__ __align__(16) __bf16 sA[2][512 * BK];  // 2 x 32 KB
  __shared__ __align__(16) __bf16 sB[2][32 * BK];   // 2 x 2 KB

  const int tid  = threadIdx.x;
  const int lane = tid & 63;
  const int wave = tid >> 6;          // 0..3 -> rows [128w, 128w+128)
  const int m16  = lane & 15;
  const int q    = lane >> 4;

  const int bn0 = blockIdx.x * 32;

  const float lmin  = logmin[0];
  const float slope = (logmax[0] - lmin) * (1.0f / 254.0f);

  // A staging map: chunk j (0..7): row = j*64 + t/4, koff = (t&3)*8.
  // Wave-load = 16 rows x 64 B  -> 16 lines (vs 64 for the direct gather).
  const int ar = tid >> 2;            // 0..63
  const int ac = (tid & 3) * 8;
  const __bf16* gA = A + (size_t)ar * K + ac;   // + j*64*K + kt
  const int lA = ar * BK + ac;                  // + j*64*BK  (elements)

  // B staging map: row = t/8 (0..31), koff = (t&7)*4.
  const int br = tid >> 3;
  const int bc = (tid & 7) * 4;
  const int* gS = stored + (size_t)(bn0 + br) * K + bc;
  const int* gG = sign   + (size_t)(bn0 + br) * K + bc;
  const int lB = br * BK + bc;

  floatx4 acc[8][2] = {};

  // Validated decode (rounds 1,2,4): w = sign * exp(lmin + (255-s)*slope)
#define DECODE_STORE(sv, gv, dst)                                              \
  {                                                                            \
    bf16x4 wv;                                                                 \
    wv[0] = (__bf16)(__expf(fmaf((float)(255 - (sv).x), slope, lmin)) *        \
                     (float)(gv).x);                                           \
    wv[1] = (__bf16)(__expf(fmaf((float)(255 - (sv).y), slope, lmin)) *        \
                     (float)(gv).y);                                           \
    wv[2] = (__bf16)(__expf(fmaf((float)(255 - (sv).z), slope, lmin)) *        \
                     (float)(gv).z);                                           \
    wv[3] = (__bf16)(__expf(fmaf((float)(255 - (sv).w), slope, lmin)) *        \
                     (float)(gv).w);                                           \
    *(bf16x4*)(dst) = wv;                                                      \
  }

  // ---- Prologue: stage tile kt=0 into buffer 0 ----
  {
    intx4 sv = __builtin_nontemporal_load((const intx4*)gS);
    intx4 gv = __builtin_nontemporal_load((const intx4*)gG);
#pragma unroll
    for (int j = 0; j < 8; ++j) {
      bf16x8 av = *(const bf16x8*)(gA + (size_t)(j * 64) * K);
      *(bf16x8*)&sA[0][lA + j * 64 * BK] = av;
    }
    DECODE_STORE(sv, gv, &sB[0][lB]);
  }
  // Int prefetch pipe: s0/g0 -> kt=32, s1/g1 -> kt=64.
  intx4 s0 = __builtin_nontemporal_load((const intx4*)(gS + BK));
  intx4 g0 = __builtin_nontemporal_load((const intx4*)(gG + BK));
  intx4 s1 = __builtin_nontemporal_load((const intx4*)(gS + 2 * BK));
  intx4 g1 = __builtin_nontemporal_load((const intx4*)(gG + 2 * BK));

  // ---- Main loop: one barrier per K-step ----
  int p = 0;
  for (int kt = 0; kt < K; kt += BK, p ^= 1) {
    __syncthreads();  // buf p (staged last iter) visible; p^1 readers done

    // Clamped next-tile indices (dummy work on the tail iter; buffer p^1
    // is never read after the last barrier, so garbage there is harmless).
    const int ktA = (kt + BK) < K ? (kt + BK) : 0;
    const int ktI = (kt + 3 * BK) < K ? (kt + 3 * BK) : 0;

    // Issue A global loads for tile kt+BK (L2-hit, ~300 cyc to cover).
    bf16x8 av[8];
#pragma unroll
    for (int j = 0; j < 8; ++j)
      av[j] = *(const bf16x8*)(gA + (size_t)(j * 64) * K + ktA);

    // Read current frags from buf p.
    bf16x8 afr[8], bfr[2];
#pragma unroll
    for (int i = 0; i < 8; ++i)
      afr[i] = *(const bf16x8*)&sA[p][(wave * 128 + i * 16 + m16) * BK + q * 8];
#pragma unroll
    for (int i = 0; i < 2; ++i)
      bfr[i] = *(const bf16x8*)&sB[p][(i * 16 + m16) * BK + q * 8];

    // Decode ints (loaded 2 iters ago) for kt+BK; rotate prefetch pipe.
    DECODE_STORE(s0, g0, &sB[p ^ 1][lB]);
    s0 = s1; g0 = g1;
    s1 = __builtin_nontemporal_load((const intx4*)(gS + ktI));
    g1 = __builtin_nontemporal_load((const intx4*)(gG + ktI));

    // MFMA on current tile.
#pragma unroll
    for (int mi = 0; mi < 8; ++mi)
#pragma unroll
      for (int ni = 0; ni < 2; ++ni)
        acc[mi][ni] = __builtin_amdgcn_mfma_f32_16x16x32_bf16(
            afr[mi], bfr[ni], acc[mi][ni], 0, 0, 0);

    // Stage A tile kt+BK into buf p^1 (vmcnt wait lands here; loads were
    // issued ~400 cycles ago).
#pragma unroll
    for (int j = 0; j < 8; ++j)
      *(bf16x8*)&sA[p ^ 1][lA + j * 64 * BK] = av[j];
  }

  // Epilogue. C/D layout: col = lane&15, row = q*4 + reg  [m89]
#pragma unroll
  for (int ni = 0; ni < 2; ++ni) {
    const int col = bn0 + ni * 16 + m16;
    const float sc = scale[col];
    const float bb = bias[col] * sc;
#pragma unroll
    for (int mi = 0; mi < 8; ++mi) {
#pragma unroll
      for (int r = 0; r < 4; ++r) {
        const int row = wave * 128 + mi * 16 + q * 4 + r;
        out[(size_t)row * N + col] = acc[mi][ni][r] * sc + bb;
      }
    }
  }
#undef DECODE_STORE
}

// ---------------------------------------------------------------------------
extern "C" void kernel_launch(void* const* d_in, const int* in_sizes, int n_in,
                              void* d_out, int out_size, void* d_ws, size_t ws_size,
                              hipStream_t stream) {
  const float* x      = (const float*)d_in[0];
  const int*   stored = (const int*)d_in[1];
  const int*   sign   = (const int*)d_in[2];
  const float* logmin = (const float*)d_in[3];
  const float* logmax = (const float*)d_in[4];
  const float* scale  = (const float*)d_in[5];
  const float* bias   = (const float*)d_in[6];
  float* out = (float*)d_out;

  __bf16* wsX = (__bf16*)d_ws;  // 512*4096 bf16 = 4 MB

  conv_x_kernel<<<(B_DIM * (IN_DIM / 4)) / 256, 256, 0, stream>>>(x, wsX);
  fused_gemm_kernel<<<OUT_DIM / 32, 256, 0, stream>>>(
      wsX, stored, sign, logmin, logmax, scale, bias, out);
}

// Round 6
// 482.113 us; speedup vs baseline: 1.1008x; 1.0596x over previous
//
#include <hip/hip_runtime.h>
#include <hip/hip_bf16.h>

// Problem constants
#define B_DIM   512
#define IN_DIM  4096
#define OUT_DIM 11008

typedef __bf16 bf16x4  __attribute__((ext_vector_type(4)));
typedef __bf16 bf16x8  __attribute__((ext_vector_type(8)));
typedef float  floatx4 __attribute__((ext_vector_type(4)));
typedef int    intx4   __attribute__((ext_vector_type(4)));

// ---------------------------------------------------------------------------
// Pre-pass: x fp32 -> bf16 in MFMA A-fragment order.
// Tile (kidx, mt) = 16 rows (m) x 32 cols (k); stored as 64 lanes x 16 B
// contiguous (1 KB), lane l holds A[mt*16 + (l&15)][kidx*32 + (l>>4)*8 + j].
// Af index of tile = kidx*32 + mt  (k-major).  512x4096 -> 4 MB.
// ---------------------------------------------------------------------------
__global__ __launch_bounds__(256) void conv_reorder_kernel(
    const float* __restrict__ x, __bf16* __restrict__ Af) {
  int t = blockIdx.x * 256 + threadIdx.x;   // 16B-chunk id, 0..262143
  int lane = t & 63, tile = t >> 6;
  int mt = tile & 31, kidx = tile >> 5;
  int m16 = lane & 15, q = lane >> 4;
  const float* src = x + (size_t)(mt * 16 + m16) * IN_DIM + kidx * 32 + q * 8;
  float4 a = *(const float4*)src;
  float4 b = *(const float4*)(src + 4);
  bf16x8 o;
  o[0] = (__bf16)a.x; o[1] = (__bf16)a.y; o[2] = (__bf16)a.z; o[3] = (__bf16)a.w;
  o[4] = (__bf16)b.x; o[5] = (__bf16)b.y; o[6] = (__bf16)b.z; o[7] = (__bf16)b.w;
  ((bf16x8*)Af)[t] = o;
}

// ---------------------------------------------------------------------------
// Fused decode + GEMM.  C(512x11008) = A * W^T, W decoded on the fly.
// BM=512 (ints read EXACTLY once), BN=32, BK=128 (4 substeps of 32).
// Grid = 344 blocks x 256 thr (4 waves). Wave w: rows [128w,128w+128) x 32
// cols: 8x2 frags of mfma_f32_16x16x32_bf16, acc = 64 VGPR.
//  - A-frags: direct coalesced loads from fragment-ordered Af (L2-resident).
//    No LDS for A -> A never interacts with the barrier.
//  - B: int4 loads issued at iter top for iter k+1; decoded + ds_written at
//    iter END (after ~2000 cyc of MFMA work covers HBM latency). Nothing is
//    in flight when the barrier's vmcnt(0) drain executes.
//  - 32 barriers total (vs 128 in rounds 2-5).
// ---------------------------------------------------------------------------
__global__ __launch_bounds__(256, 2) void fused_gemm_kernel(
    const __bf16* __restrict__ Af,      // fragment-ordered A (ws)
    const int* __restrict__ stored,     // 11008 x 4096 int32 in [1,255]
    const int* __restrict__ sign,       // 11008 x 4096 int32 in {-1,+1}
    const float* __restrict__ logmin, const float* __restrict__ logmax,
    const float* __restrict__ scale, const float* __restrict__ bias,
    float* __restrict__ out) {          // 512 x 11008 fp32
  constexpr int K = IN_DIM, N = OUT_DIM;
  constexpr int SBS = 136;              // sB row stride in elems (+8 pad)

  __shared__ __align__(16) __bf16 sB[2][32 * SBS];  // 2 x 8.5 KB

  const int tid  = threadIdx.x;
  const int lane = tid & 63;
  const int wave = tid >> 6;            // 0..3 -> rows [128w, 128w+128)
  const int m16  = lane & 15;
  const int q    = lane >> 4;

  const int bn0 = blockIdx.x * 32;

  const float lmin  = logmin[0];
  const float slope = (logmax[0] - lmin) * (1.0f / 254.0f);

  // Int staging: thread t -> B row r = t>>3 (0..31), k-base (t&7)*16.
  // 16 ints per array per thread per iter = 4x int4, rows read 512 B
  // contiguous -> fully coalesced.
  const int r  = tid >> 3;
  const int kb = (tid & 7) * 16;
  const int* gS = stored + (size_t)(bn0 + r) * K + kb;
  const int* gG = sign   + (size_t)(bn0 + r) * K + kb;

  // A-frag base: per (kidx, mi) add (kidx*32 + mi)*512 elems.
  const __bf16* gA = Af + (size_t)(wave * 8) * 512 + (size_t)lane * 8;

  floatx4 acc[8][2] = {};

  // Validated decode (rounds 1,2,4,5): w = sign * exp(lmin + (255-s)*slope)
#define DEC4(sv, gv, wv, base)                                                 \
  wv[base + 0] = (__bf16)(__expf(fmaf((float)(255 - (sv).x), slope, lmin)) *   \
                          (float)(gv).x);                                      \
  wv[base + 1] = (__bf16)(__expf(fmaf((float)(255 - (sv).y), slope, lmin)) *   \
                          (float)(gv).y);                                      \
  wv[base + 2] = (__bf16)(__expf(fmaf((float)(255 - (sv).z), slope, lmin)) *   \
                          (float)(gv).z);                                      \
  wv[base + 3] = (__bf16)(__expf(fmaf((float)(255 - (sv).w), slope, lmin)) *   \
                          (float)(gv).w)

  intx4 sv[4], gv[4];

  // ---- Prologue: decode iter 0's B tile into sB[0] ----
#pragma unroll
  for (int j = 0; j < 4; ++j) {
    sv[j] = __builtin_nontemporal_load((const intx4*)(gS + j * 4));
    gv[j] = __builtin_nontemporal_load((const intx4*)(gG + j * 4));
  }
  {
    bf16x8 w0, w1;
    DEC4(sv[0], gv[0], w0, 0); DEC4(sv[1], gv[1], w0, 4);
    DEC4(sv[2], gv[2], w1, 0); DEC4(sv[3], gv[3], w1, 4);
    *(bf16x8*)&sB[0][r * SBS + kb]     = w0;
    *(bf16x8*)&sB[0][r * SBS + kb + 8] = w1;
  }

  // ---- Main loop: 32 iterations, ONE barrier each ----
  int p = 0;
  for (int it = 0; it < 32; ++it, p ^= 1) {
    __syncthreads();                    // sB[p] ready; nothing else in flight

    const bool more = (it + 1) < 32;
    const int  ktn  = more ? (it + 1) * 128 : 0;  // clamped dummy on tail

    // Issue int loads for iter it+1 NOW; consumed ~2000 cycles later.
#pragma unroll
    for (int j = 0; j < 4; ++j) {
      sv[j] = __builtin_nontemporal_load((const intx4*)(gS + ktn + j * 4));
      gv[j] = __builtin_nontemporal_load((const intx4*)(gG + ktn + j * 4));
    }

    // 4 substeps of K=32.
#pragma unroll
    for (int kk = 0; kk < 4; ++kk) {
      const int kidx = it * 4 + kk;
      bf16x8 afr[8], bfr[2];
#pragma unroll
      for (int mi = 0; mi < 8; ++mi)
        afr[mi] = *(const bf16x8*)(gA + ((size_t)kidx * 32 + mi) * 512);
#pragma unroll
      for (int ni = 0; ni < 2; ++ni)
        bfr[ni] = *(const bf16x8*)&sB[p][(ni * 16 + m16) * SBS + kk * 32 + q * 8];
#pragma unroll
      for (int mi = 0; mi < 8; ++mi)
#pragma unroll
        for (int ni = 0; ni < 2; ++ni)
          acc[mi][ni] = __builtin_amdgcn_mfma_f32_16x16x32_bf16(
              afr[mi], bfr[ni], acc[mi][ni], 0, 0, 0);
    }

    // Decode iter it+1's ints (issued at iter top) into sB[p^1].
    if (more) {
      bf16x8 w0, w1;
      DEC4(sv[0], gv[0], w0, 0); DEC4(sv[1], gv[1], w0, 4);
      DEC4(sv[2], gv[2], w1, 0); DEC4(sv[3], gv[3], w1, 4);
      *(bf16x8*)&sB[p ^ 1][r * SBS + kb]     = w0;
      *(bf16x8*)&sB[p ^ 1][r * SBS + kb + 8] = w1;
    }
  }

  // Epilogue. C/D layout: col = lane&15, row = q*4 + reg  [m89, validated R4/5]
#pragma unroll
  for (int ni = 0; ni < 2; ++ni) {
    const int col = bn0 + ni * 16 + m16;
    const float sc = scale[col];
    const float bb = bias[col] * sc;
#pragma unroll
    for (int mi = 0; mi < 8; ++mi) {
#pragma unroll
      for (int rr = 0; rr < 4; ++rr) {
        const int row = wave * 128 + mi * 16 + q * 4 + rr;
        out[(size_t)row * N + col] = acc[mi][ni][rr] * sc + bb;
      }
    }
  }
#undef DEC4
}

// ---------------------------------------------------------------------------
extern "C" void kernel_launch(void* const* d_in, const int* in_sizes, int n_in,
                              void* d_out, int out_size, void* d_ws, size_t ws_size,
                              hipStream_t stream) {
  const float* x      = (const float*)d_in[0];
  const int*   stored = (const int*)d_in[1];
  const int*   sign   = (const int*)d_in[2];
  const float* logmin = (const float*)d_in[3];
  const float* logmax = (const float*)d_in[4];
  const float* scale  = (const float*)d_in[5];
  const float* bias   = (const float*)d_in[6];
  float* out = (float*)d_out;

  __bf16* wsAf = (__bf16*)d_ws;  // fragment-ordered A: 4 MB

  // 512*4096/8 = 262144 chunks -> 1024 blocks
  conv_reorder_kernel<<<(B_DIM * IN_DIM / 8) / 256, 256, 0, stream>>>(x, wsAf);
  fused_gemm_kernel<<<OUT_DIM / 32, 256, 0, stream>>>(
      wsAf, stored, sign, logmin, logmax, scale, bias, out);
}